// Round 3
// baseline (619.817 us; speedup 1.0000x reference)
//
#include <hip/hip_runtime.h>
#include <hip/hip_bf16.h>

#define NNODES 16384
#define KNEI 25
#define NREL 3
#define DIM 256
#define OUTD 256
#define NTOTAL 100000

typedef __attribute__((ext_vector_type(8))) short short8;
typedef __attribute__((ext_vector_type(4))) float f32x4;

static __device__ __forceinline__ unsigned short f2bf(float x) {
    union { float f; unsigned u; } v; v.f = x;
    unsigned r = v.u + 0x7fff + ((v.u >> 16) & 1);   // RNE
    return (unsigned short)(r >> 16);
}

// ---------------------------------------------------------------------------
// prep_M: fold W_rel/W_self into W_comp -> bf16 M[256][1024].
// M[o][slot*256+d] = sum_j W_comp[o][slot*256+j] * Wslot[j][d]
// ---------------------------------------------------------------------------
__global__ __launch_bounds__(256) void prep_M(
        const float* __restrict__ W_self,
        const float* __restrict__ W_rel,
        const float* __restrict__ W_comp,
        unsigned short* __restrict__ M) {
    const int slot = blockIdx.x >> 6;
    const int o0   = (blockIdx.x & 63) * 4;
    const int t    = threadIdx.x;            // d = t
    const float* __restrict__ Wslot = (slot < NREL)
        ? (W_rel + (size_t)slot * OUTD * DIM) : W_self;
    __shared__ float C[4 * 256];
#pragma unroll
    for (int oi = 0; oi < 4; ++oi)
        C[oi * 256 + t] = W_comp[(size_t)(o0 + oi) * 1024 + slot * 256 + t];
    __syncthreads();
    float acc[4] = {0.f, 0.f, 0.f, 0.f};
    for (int j = 0; j < 256; j += 8) {
#pragma unroll
        for (int u = 0; u < 8; ++u) {
            const float wv = Wslot[(size_t)(j + u) * 256 + t];   // coalesced
#pragma unroll
            for (int oi = 0; oi < 4; ++oi)
                acc[oi] += C[oi * 256 + j + u] * wv;             // LDS broadcast
        }
    }
#pragma unroll
    for (int oi = 0; oi < 4; ++oi)
        M[(size_t)(o0 + oi) * 1024 + slot * 256 + t] = f2bf(acc[oi]);
}

// ---------------------------------------------------------------------------
// gather_kernel: relation-phased gather + K-mean -> bf16 G[16384][1024] (ws).
// MLP-first restructure: all 25 indices loaded up front, then all 25 row
// loads issued into 25 distinct float4 regs BEFORE any accumulate.
// __launch_bounds__(256,2) -> ~256-VGPR budget, 8 waves/CU, ~200 KB/CU in
// flight. (Round-2 version at VGPR=48 had ~0.5 loads/lane in flight ->
// 5.6 B/cyc/CU, latency-bound.)
// ---------------------------------------------------------------------------
__global__ __launch_bounds__(256, 2) void gather_kernel(
        const int*   __restrict__ nodes,
        const int*   __restrict__ neigh_idx,
        const float* __restrict__ table_self,
        const float* __restrict__ tables_to,
        unsigned short* __restrict__ G) {
    const int b    = blockIdx.x;
    const int r    = b >> 10;            // 0..3
    const int blk  = b & 1023;
    const int wave = threadIdx.x >> 6;
    const int lane = threadIdx.x & 63;
    const int d4   = lane * 4;           // dims [d4, d4+4)

    if (r < NREL) {
        const float* __restrict__ tab = tables_to + (size_t)r * NTOTAL * DIM;
        const float invK = 1.0f / (float)KNEI;
#pragma unroll 1
        for (int i = 0; i < 4; ++i) {
            const int n = blk * 16 + wave * 4 + i;
            const int* __restrict__ idxp =
                neigh_idx + ((size_t)r * NNODES + n) * KNEI;
            int idx[KNEI];
#pragma unroll
            for (int j = 0; j < KNEI; ++j) idx[j] = idxp[j];
            float4 v[KNEI];
#pragma unroll
            for (int j = 0; j < KNEI; ++j)
                v[j] = *(const float4*)(tab + (size_t)idx[j] * DIM + d4);
            // pairwise-ish reduce (waits retire oldest loads first)
            float4 s = v[0];
#pragma unroll
            for (int j = 1; j < KNEI; ++j) {
                s.x += v[j].x; s.y += v[j].y;
                s.z += v[j].z; s.w += v[j].w;
            }
            ushort4 pk;
            pk.x = f2bf(s.x * invK); pk.y = f2bf(s.y * invK);
            pk.z = f2bf(s.z * invK); pk.w = f2bf(s.w * invK);
            *(ushort4*)(G + (size_t)n * 1024 + r * 256 + d4) = pk;
        }
    } else {
        // self slot (3): plain gather, no mean
#pragma unroll
        for (int i = 0; i < 4; ++i) {
            const int n = blk * 16 + wave * 4 + i;
            const float4 v =
                *(const float4*)(table_self + (size_t)nodes[n] * DIM + d4);
            ushort4 pk;
            pk.x = f2bf(v.x); pk.y = f2bf(v.y);
            pk.z = f2bf(v.z); pk.w = f2bf(v.w);
            *(ushort4*)(G + (size_t)n * 1024 + 3 * 256 + d4) = pk;
        }
    }
}

// ---------------------------------------------------------------------------
// gemm_kernel: per block, 16 nodes. Stage G tile [16][1024] bf16 in LDS,
// h = relu(G @ M^T) via mfma 16x16x32 bf16, bag-mean(8) epilogue.
// (verified rounds 1-2, unchanged)
// ---------------------------------------------------------------------------
#define GSTRIDE 1032   // 1024 + 8 bf16 pad

__global__ __launch_bounds__(256, 4) void gemm_kernel(
        const unsigned short* __restrict__ G,
        const unsigned short* __restrict__ M,
        float* __restrict__ out) {
    __shared__ unsigned short A[16 * GSTRIDE];   // 33 KB

    const int t    = threadIdx.x;
    const int wave = t >> 6;
    const int lane = t & 63;
    const int quad = lane >> 4;
    const int l16  = lane & 15;

    const unsigned short* gsrc = G + (size_t)blockIdx.x * 16 * 1024;
#pragma unroll
    for (int rnd = 0; rnd < 8; ++rnd) {
        const int l   = rnd * 2048 + t * 8;
        const int row = l >> 10;
        const int col = l & 1023;
        *(short8*)&A[row * GSTRIDE + col] = *(const short8*)(gsrc + l);
    }
    __syncthreads();

    f32x4 acc[4];
#pragma unroll
    for (int ct = 0; ct < 4; ++ct) acc[ct] = (f32x4){0.f, 0.f, 0.f, 0.f};

    for (int k0 = 0; k0 < 1024; k0 += 32) {
        const short8 a = *(const short8*)&A[l16 * GSTRIDE + k0 + quad * 8];
#pragma unroll
        for (int ct = 0; ct < 4; ++ct) {
            const int o = wave * 64 + ct * 16 + l16;
            const short8 bfrag =
                *(const short8*)(M + (size_t)o * 1024 + k0 + quad * 8);
            acc[ct] = __builtin_amdgcn_mfma_f32_16x16x32_bf16(a, bfrag, acc[ct], 0, 0, 0);
        }
    }

    // C/D: col = l16, row(node) = quad*4 + reg. relu -> sum 4 regs ->
    // shfl_xor(16) combines quad pairs => bag of 8 -> /8
    const size_t orow0 = (size_t)blockIdx.x * 2;
#pragma unroll
    for (int ct = 0; ct < 4; ++ct) {
        float s = fmaxf(acc[ct][0], 0.f) + fmaxf(acc[ct][1], 0.f)
                + fmaxf(acc[ct][2], 0.f) + fmaxf(acc[ct][3], 0.f);
        s += __shfl_xor(s, 16, 64);
        s *= 0.125f;
        const int col = wave * 64 + ct * 16 + l16;
        if (quad == 0)      out[orow0 * 256 + col]       = s;
        else if (quad == 2) out[(orow0 + 1) * 256 + col] = s;
    }
}

// ---------------------------------------------------------------------------
// Fallback fused kernel (round-1 verified) if ws is too small for G.
// ---------------------------------------------------------------------------
__global__ __launch_bounds__(256, 4) void encoder_main(
        const int*   __restrict__ nodes,
        const int*   __restrict__ neigh_idx,
        const float* __restrict__ table_self,
        const float* __restrict__ tables_to,
        const unsigned short* __restrict__ M,
        float* __restrict__ out) {
    __shared__ unsigned short Gt[16 * GSTRIDE];
    const int tid  = threadIdx.x;
    const int wave = tid >> 6;
    const int lane = tid & 63;
    const int n0   = blockIdx.x * 16;
    {
        const int d4 = lane * 4;
        const float invK = 1.0f / (float)KNEI;
#pragma unroll
        for (int i = 0; i < 4; ++i) {
            const int li = wave * 4 + i;
            const int n  = n0 + li;
#pragma unroll
            for (int r = 0; r < NREL; ++r) {
                const int* idxp = neigh_idx + ((size_t)r * NNODES + n) * KNEI;
                const float* tab = tables_to + (size_t)r * NTOTAL * DIM;
                float4 acc = make_float4(0.f, 0.f, 0.f, 0.f);
#pragma unroll 5
                for (int j = 0; j < KNEI; ++j) {
                    const float4 v = *(const float4*)(tab + (size_t)idxp[j] * DIM + d4);
                    acc.x += v.x; acc.y += v.y; acc.z += v.z; acc.w += v.w;
                }
                ushort4 pk;
                pk.x = f2bf(acc.x * invK); pk.y = f2bf(acc.y * invK);
                pk.z = f2bf(acc.z * invK); pk.w = f2bf(acc.w * invK);
                *(ushort4*)&Gt[li * GSTRIDE + r * 256 + d4] = pk;
            }
            {
                const float4 v = *(const float4*)(table_self + (size_t)nodes[n] * DIM + d4);
                ushort4 pk;
                pk.x = f2bf(v.x); pk.y = f2bf(v.y);
                pk.z = f2bf(v.z); pk.w = f2bf(v.w);
                *(ushort4*)&Gt[li * GSTRIDE + 3 * 256 + d4] = pk;
            }
        }
    }
    __syncthreads();
    const int quad = lane >> 4;
    const int l16  = lane & 15;
    f32x4 acc[4];
#pragma unroll
    for (int ct = 0; ct < 4; ++ct) acc[ct] = (f32x4){0.f, 0.f, 0.f, 0.f};
    for (int k0 = 0; k0 < 1024; k0 += 32) {
        const short8 a = *(const short8*)&Gt[l16 * GSTRIDE + k0 + quad * 8];
#pragma unroll
        for (int ct = 0; ct < 4; ++ct) {
            const int o = wave * 64 + ct * 16 + l16;
            const short8 b = *(const short8*)(M + (size_t)o * 1024 + k0 + quad * 8);
            acc[ct] = __builtin_amdgcn_mfma_f32_16x16x32_bf16(a, b, acc[ct], 0, 0, 0);
        }
    }
    const size_t orow0 = (size_t)blockIdx.x * 2;
#pragma unroll
    for (int ct = 0; ct < 4; ++ct) {
        float s = fmaxf(acc[ct][0], 0.f) + fmaxf(acc[ct][1], 0.f)
                + fmaxf(acc[ct][2], 0.f) + fmaxf(acc[ct][3], 0.f);
        s += __shfl_xor(s, 16, 64);
        s *= 0.125f;
        const int col = wave * 64 + ct * 16 + l16;
        if (quad == 0)      out[orow0 * 256 + col]       = s;
        else if (quad == 2) out[(orow0 + 1) * 256 + col] = s;
    }
}

extern "C" void kernel_launch(void* const* d_in, const int* in_sizes, int n_in,
                              void* d_out, int out_size, void* d_ws, size_t ws_size,
                              hipStream_t stream) {
    const int*   nodes  = (const int*)  d_in[0];
    const int*   neigh  = (const int*)  d_in[1];
    const float* tself  = (const float*)d_in[2];
    const float* tto    = (const float*)d_in[3];
    const float* wself  = (const float*)d_in[4];
    const float* wrel   = (const float*)d_in[5];
    const float* wcomp  = (const float*)d_in[6];
    float* outp = (float*)d_out;

    unsigned short* M = (unsigned short*)d_ws;              // 512 KB
    const size_t g_off  = 1u << 20;                         // 1 MB aligned
    const size_t g_size = (size_t)NNODES * 1024 * 2;        // 32 MB
    prep_M<<<256, 256, 0, stream>>>(wself, wrel, wcomp, M);
    if (ws_size >= g_off + g_size) {
        unsigned short* G = (unsigned short*)((char*)d_ws + g_off);
        gather_kernel<<<4096, 256, 0, stream>>>(nodes, neigh, tself, tto, G);
        gemm_kernel<<<1024, 256, 0, stream>>>(G, M, outp);
    } else {
        encoder_main<<<1024, 256, 0, stream>>>(nodes, neigh, tself, tto, M, outp);
    }
}

// Round 4
// 602.874 us; speedup vs baseline: 1.0281x; 1.0281x over previous
//
#include <hip/hip_runtime.h>
#include <hip/hip_bf16.h>

#define NNODES 16384
#define KNEI 25
#define NREL 3
#define DIM 256
#define OUTD 256
#define NTOTAL 100000

typedef __attribute__((ext_vector_type(8))) short short8;
typedef __attribute__((ext_vector_type(4))) float f32x4;

static __device__ __forceinline__ unsigned short f2bf(float x) {
    union { float f; unsigned u; } v; v.f = x;
    unsigned r = v.u + 0x7fff + ((v.u >> 16) & 1);   // RNE
    return (unsigned short)(r >> 16);
}

// ---------------------------------------------------------------------------
// prep_M: fold W_rel/W_self into W_comp -> bf16 M[256][1024].
// M[o][slot*256+d] = sum_j W_comp[o][slot*256+j] * Wslot[j][d]
// (round-2 version, ~10 us)
// ---------------------------------------------------------------------------
__global__ __launch_bounds__(256) void prep_M(
        const float* __restrict__ W_self,
        const float* __restrict__ W_rel,
        const float* __restrict__ W_comp,
        unsigned short* __restrict__ M) {
    const int slot = blockIdx.x >> 6;
    const int o0   = (blockIdx.x & 63) * 4;
    const int t    = threadIdx.x;            // d = t
    const float* __restrict__ Wslot = (slot < NREL)
        ? (W_rel + (size_t)slot * OUTD * DIM) : W_self;
    __shared__ float C[4 * 256];
#pragma unroll
    for (int oi = 0; oi < 4; ++oi)
        C[oi * 256 + t] = W_comp[(size_t)(o0 + oi) * 1024 + slot * 256 + t];
    __syncthreads();
    float acc[4] = {0.f, 0.f, 0.f, 0.f};
    for (int j = 0; j < 256; j += 8) {
#pragma unroll
        for (int u = 0; u < 8; ++u) {
            const float wv = Wslot[(size_t)(j + u) * 256 + t];   // coalesced
#pragma unroll
            for (int oi = 0; oi < 4; ++oi)
                acc[oi] += C[oi * 256 + j + u] * wv;             // LDS broadcast
        }
    }
#pragma unroll
    for (int oi = 0; oi < 4; ++oi)
        M[(size_t)(o0 + oi) * 1024 + slot * 256 + t] = f2bf(acc[oi]);
}

// ---------------------------------------------------------------------------
// fused_kernel: 16 nodes per block, 256 threads.
// Phase 1: gather + K-mean straight into bf16 LDS tile G[16][1024].
//   - 25 table-row loads per (node,rel) fully unrolled into 25 float4 regs
//     (round-3 structure: at the ~3.4 TB/s read-path ceiling).
//   - indices via readfirstlane -> wave-uniform s_load (frees ~25 VGPRs).
//   - no G round-trip through HBM (saves 32 MB write + 32 MB fetch vs split).
// Phase 2: h = relu(G @ M^T) via mfma 16x16x32 bf16, bag-mean(8) epilogue
//   (verified rounds 1-3). Phase 2 of one block overlaps phase 1 of
//   co-resident blocks (MFMA/VMEM pipes are independent).
// ---------------------------------------------------------------------------
#define GSTRIDE 1032   // 1024 + 8 bf16 pad

__global__ __launch_bounds__(256, 3) void fused_kernel(
        const int*   __restrict__ nodes,
        const int*   __restrict__ neigh_idx,
        const float* __restrict__ table_self,
        const float* __restrict__ tables_to,
        const unsigned short* __restrict__ M,
        float* __restrict__ out) {
    __shared__ unsigned short G[16 * GSTRIDE];   // 33 KB

    const int t    = threadIdx.x;
    const int wave = t >> 6;
    const int lane = t & 63;
    const int d4   = lane * 4;                   // dims [d4, d4+4)
    const int n0   = blockIdx.x * 16;
    const float invK = 1.0f / (float)KNEI;

    // ---- Phase 1: gather + mean -> LDS ----
#pragma unroll 1
    for (int i = 0; i < 4; ++i) {
        const int li = wave * 4 + i;                       // local row in G
        const int nu = __builtin_amdgcn_readfirstlane(n0 + li);
#pragma unroll 1
        for (int r = 0; r < NREL; ++r) {
            const int* __restrict__ idxp =
                neigh_idx + ((size_t)r * NNODES + nu) * KNEI;   // uniform
            const float* __restrict__ tab =
                tables_to + (size_t)r * NTOTAL * DIM;
            float4 v[KNEI];
#pragma unroll
            for (int j = 0; j < KNEI; ++j)
                v[j] = *(const float4*)(tab + (size_t)idxp[j] * DIM + d4);
            float4 s = v[0];
#pragma unroll
            for (int j = 1; j < KNEI; ++j) {
                s.x += v[j].x; s.y += v[j].y;
                s.z += v[j].z; s.w += v[j].w;
            }
            ushort4 pk;
            pk.x = f2bf(s.x * invK); pk.y = f2bf(s.y * invK);
            pk.z = f2bf(s.z * invK); pk.w = f2bf(s.w * invK);
            *(ushort4*)&G[li * GSTRIDE + r * 256 + d4] = pk;
        }
        {   // self slot (3)
            const int row = __builtin_amdgcn_readfirstlane(nodes[nu]);
            const float4 v =
                *(const float4*)(table_self + (size_t)row * DIM + d4);
            ushort4 pk;
            pk.x = f2bf(v.x); pk.y = f2bf(v.y);
            pk.z = f2bf(v.z); pk.w = f2bf(v.w);
            *(ushort4*)&G[li * GSTRIDE + 3 * 256 + d4] = pk;
        }
    }
    __syncthreads();

    // ---- Phase 2: GEMM + relu + bag-mean ----
    const int quad = lane >> 4;
    const int l16  = lane & 15;
    f32x4 acc[4];
#pragma unroll
    for (int ct = 0; ct < 4; ++ct) acc[ct] = (f32x4){0.f, 0.f, 0.f, 0.f};

    for (int k0 = 0; k0 < 1024; k0 += 32) {
        const short8 a = *(const short8*)&G[l16 * GSTRIDE + k0 + quad * 8];
#pragma unroll
        for (int ct = 0; ct < 4; ++ct) {
            const int o = wave * 64 + ct * 16 + l16;
            const short8 b =
                *(const short8*)(M + (size_t)o * 1024 + k0 + quad * 8);
            acc[ct] = __builtin_amdgcn_mfma_f32_16x16x32_bf16(a, b, acc[ct], 0, 0, 0);
        }
    }

    // C/D: col = l16, row(node) = quad*4 + reg. relu -> sum 4 regs ->
    // shfl_xor(16) combines quad pairs => bag of 8 -> /8
    const size_t orow0 = (size_t)blockIdx.x * 2;
#pragma unroll
    for (int ct = 0; ct < 4; ++ct) {
        float s = fmaxf(acc[ct][0], 0.f) + fmaxf(acc[ct][1], 0.f)
                + fmaxf(acc[ct][2], 0.f) + fmaxf(acc[ct][3], 0.f);
        s += __shfl_xor(s, 16, 64);
        s *= 0.125f;
        const int col = wave * 64 + ct * 16 + l16;
        if (quad == 0)      out[orow0 * 256 + col]       = s;
        else if (quad == 2) out[(orow0 + 1) * 256 + col] = s;
    }
}

extern "C" void kernel_launch(void* const* d_in, const int* in_sizes, int n_in,
                              void* d_out, int out_size, void* d_ws, size_t ws_size,
                              hipStream_t stream) {
    const int*   nodes  = (const int*)  d_in[0];
    const int*   neigh  = (const int*)  d_in[1];
    const float* tself  = (const float*)d_in[2];
    const float* tto    = (const float*)d_in[3];
    const float* wself  = (const float*)d_in[4];
    const float* wrel   = (const float*)d_in[5];
    const float* wcomp  = (const float*)d_in[6];
    float* outp = (float*)d_out;

    unsigned short* M = (unsigned short*)d_ws;   // 512 KB in ws
    prep_M<<<256, 256, 0, stream>>>(wself, wrel, wcomp, M);
    fused_kernel<<<1024, 256, 0, stream>>>(nodes, neigh, tself, tto, M, outp);
}